// Round 6
// baseline (157.807 us; speedup 1.0000x reference)
//
#include <hip/hip_runtime.h>
#include <hip/hip_bf16.h>

// Capsule dynamic routing, round 16.
// R15 FAILED (absmax 0.19): its 16-wave fused mapping covered only n=0..15
// (q=w&3 -> n0=q*4 <= 12); capsules 16..31 never computed. NOT a barrier bug.
// R16 = R14 (known-pass, 157.5 us) + exactly ONE change: the per-j
// __syncthreads() in fused_pass_k is replaced by a hardened raw barrier
//   sched_barrier(0); s_waitcnt lgkmcnt(0); sched_barrier(0); s_barrier;
//   sched_barrier(0);
// __syncthreads emits s_waitcnt vmcnt(0) before s_barrier, draining the j+1
// prefetch every iteration (why R14's pipeline was neutral). The raw barrier
// waits LDS only; prefetched Wt/xt loads stay in flight across the softmax
// exchange. sched_barrier(0) fences pin ds_write before / ds_read after the
// barrier (guide rule #18: "memory" clobber alone does not order these).
//
// Pipeline (carry only vsumT[n][b][d]):
//   cvt_x; wsum0_cvt (W f32 read once, Wt bf16 written, uniform partials);
//   reduce(first); [fused logits+softmax+wsum; reduce] x2.  7 dispatches.
//
// x[64][2048][16] f32, W[32][2048][16][16] f32 -> v[64][32][16] f32.
// MFMA layouts (m89/m91/m120-verified): C/D col=lane&15, row=(lane>>4)*4+reg;
// A[m=lane&15][k=(lane>>4)*8+t]. wsum0 K=32 packs 2 j; fused uses K=16
// (upper half nulled via zero B).

#define J_DIM 2048
#define NCH 128            // j-chunks (16 j each)

typedef __attribute__((ext_vector_type(8))) short bf16x8;
typedef __attribute__((ext_vector_type(4))) short bf16x4;
typedef __attribute__((ext_vector_type(4))) float f32x4;

__device__ inline short f2bf(float f) {
    union { float f; unsigned u; } v; v.f = f;
    unsigned r = v.u + 0x7FFFu + ((v.u >> 16) & 1u);   // RNE
    return (short)(r >> 16);
}
__device__ inline float bf2f(short s) {
    union { unsigned u; float f; } v; v.u = ((unsigned)(unsigned short)s) << 16;
    return v.f;
}
// packed f32x2 -> bf16x2 (RNE), dst.lo = bf16(lo), dst.hi = bf16(hi)
__device__ inline int cvt_pk_bf16(float lo, float hi) {
    int r;
    asm("v_cvt_pk_bf16_f32 %0, %1, %2" : "=v"(r) : "v"(lo), "v"(hi));
    return r;
}
// Barrier WITHOUT the vmcnt(0) drain __syncthreads would emit. LDS exchange
// needs lgkmcnt(0) only; prefetched global loads stay in flight. sched_barrier
// fences pin LDS ops on the correct side (rule #18).
__device__ inline void lds_barrier() {
    __builtin_amdgcn_sched_barrier(0);
    asm volatile("s_waitcnt lgkmcnt(0)" ::: "memory");
    __builtin_amdgcn_sched_barrier(0);
    __builtin_amdgcn_s_barrier();
    __builtin_amdgcn_sched_barrier(0);
}

// x[b][j][16] f32 -> xt[j][b][16] bf16. One thread per (b,j) row.
__global__ __launch_bounds__(256)
void cvt_x_t(const float* __restrict__ x, short* __restrict__ xt) {
    const int id = blockIdx.x * 256 + threadIdx.x;   // j fast for coalesced reads
    const int j = id & (J_DIM - 1), b = id >> 11;
    const float4* s = (const float4*)(x + ((size_t)b * J_DIM + j) * 16);
    float4 q0 = s[0], q1 = s[1], q2 = s[2], q3 = s[3];
    int pk[8];
    pk[0] = cvt_pk_bf16(q0.x, q0.y); pk[1] = cvt_pk_bf16(q0.z, q0.w);
    pk[2] = cvt_pk_bf16(q1.x, q1.y); pk[3] = cvt_pk_bf16(q1.z, q1.w);
    pk[4] = cvt_pk_bf16(q2.x, q2.y); pk[5] = cvt_pk_bf16(q2.z, q2.w);
    pk[6] = cvt_pk_bf16(q3.x, q3.y); pk[7] = cvt_pk_bf16(q3.z, q3.w);
    short* d = xt + ((size_t)j * 64 + b) * 16;
    *(bf16x8*)d = *(bf16x8*)pk;
    *(bf16x8*)(d + 8) = *(bf16x8*)&pk[4];
}

// Pass 0: read W f32 once (coalesced 1KB-row bursts), convert, write
// Wt[j][n][256] bf16, accumulate UNSCALED uniform-c partials (1/32 applied
// in reduce_k is_first). grid(NCH, 8) x 256 thr.
__global__ __launch_bounds__(256)
void wsum0_cvt_k(const float* __restrict__ W, short* __restrict__ Wt,
                 const short* __restrict__ xt, short* __restrict__ sp) {
    const int t = threadIdx.x, lane = t & 63, w = t >> 6;
    const int col = lane & 15, g = lane >> 4;
    const int n = blockIdx.y * 4 + w;
    const int chunk = blockIdx.x;

    f32x4 acc[4];
#pragma unroll
    for (int bt = 0; bt < 4; ++bt) acc[bt] = (f32x4){0.f, 0.f, 0.f, 0.f};

#pragma unroll
    for (int jp = 0; jp < 8; ++jp) {
        const int jq = chunk * 16 + jp * 2 + (g >> 1);
        // lane's 8 f32 of W[n][jq] row; half-wave covers the full 1KB row
        const float4* wsrc = (const float4*)(W + ((size_t)n * J_DIM + jq) * 256 + col * 16 + (g & 1) * 8);
        float4 a = wsrc[0], b2 = wsrc[1];
        int pk[4];
        pk[0] = cvt_pk_bf16(a.x, a.y);   pk[1] = cvt_pk_bf16(a.z, a.w);
        pk[2] = cvt_pk_bf16(b2.x, b2.y); pk[3] = cvt_pk_bf16(b2.z, b2.w);
        bf16x8 af = *(bf16x8*)pk;
        *(bf16x8*)(Wt + ((size_t)jq * 32 + n) * 256 + col * 16 + (g & 1) * 8) = af;
#pragma unroll
        for (int bt = 0; bt < 4; ++bt) {
            const int b = bt * 16 + col;
            bf16x8 xr = *(const bf16x8*)(xt + ((size_t)jq * 64 + b) * 16 + (g & 1) * 8);
            acc[bt] = __builtin_amdgcn_mfma_f32_16x16x32_bf16(af, xr, acc[bt], 0, 0, 0);
        }
    }
#pragma unroll
    for (int bt = 0; bt < 4; ++bt) {
        int o[2] = { cvt_pk_bf16(acc[bt][0], acc[bt][1]),
                     cvt_pk_bf16(acc[bt][2], acc[bt][3]) };
        *(bf16x4*)(sp + (((size_t)chunk * 32 + n) * 64 + bt * 16 + col) * 16 + g * 4) = *(bf16x4*)o;
    }
}

// Fused routing pass: sp[chunk][n][b][d] = sum_{j in 16-chunk} c * u_hat for
// one 16-b tile. grid(NCH, 4) x 512 thr (8 waves x 4 n = all 32 n resident).
// 2-stage pipeline: j+1's af/xb loads issue before j's barrier and now
// genuinely stay in flight across it (raw lds_barrier, no vmcnt drain).
__global__ __launch_bounds__(512, 4)
void fused_pass_k(const short* __restrict__ Wt, const short* __restrict__ xt,
                  const float* __restrict__ vsumT, short* __restrict__ sp) {
    const int t = threadIdx.x, lane = t & 63, w = t >> 6;   // w 0..7: n-quad
    const int col = lane & 15, g = lane >> 4;
    const int chunk = blockIdx.x;          // 16-j chunk
    const int bt = blockIdx.y;             // b-tile 0..3
    const int b = bt * 16 + col;
    const int n0 = w * 4;

    __shared__ float psum[2][8][16];       // [parity][wave][b-col]

    // v is j-invariant: hoist the dot operands (vsumT[n][b][d], d-quad g)
    float4 vv[4];
#pragma unroll
    for (int q = 0; q < 4; ++q)
        vv[q] = *(const float4*)(vsumT + ((size_t)(n0 + q) * 64 + b) * 16 + g * 4);

    f32x4 acc[4];
#pragma unroll
    for (int q = 0; q < 4; ++q) acc[q] = (f32x4){0.f, 0.f, 0.f, 0.f};

    // prefetch stage for j = chunk*16
    const int j0 = chunk * 16;
    bf16x8 xb_n = (bf16x8){0, 0, 0, 0, 0, 0, 0, 0};
    if (lane < 32)
        xb_n = *(const bf16x8*)(xt + ((size_t)j0 * 64 + b) * 16 + (g & 1) * 8);
    bf16x8 af_n[4];
#pragma unroll
    for (int q = 0; q < 4; ++q)
        af_n[q] = *(const bf16x8*)(Wt + ((size_t)j0 * 32 + n0 + q) * 256 + col * 16 + g * 8);

#pragma unroll 1
    for (int jj = 0; jj < 16; ++jj) {
        // consume staged operands
        const bf16x8 xb = xb_n;
        bf16x8 af[4];
#pragma unroll
        for (int q = 0; q < 4; ++q) af[q] = af_n[q];

        // issue j+1 loads NOW -- they stay in flight across the raw barrier
        if (jj < 15) {
            const int jn = chunk * 16 + jj + 1;
            xb_n = (bf16x8){0, 0, 0, 0, 0, 0, 0, 0};
            if (lane < 32)
                xb_n = *(const bf16x8*)(xt + ((size_t)jn * 64 + b) * 16 + (g & 1) * 8);
#pragma unroll
            for (int q = 0; q < 4; ++q)
                af_n[q] = *(const bf16x8*)(Wt + ((size_t)jn * 32 + n0 + q) * 256 + col * 16 + g * 8);
        }

        f32x4 u[4];
        float e[4];
        float ps = 0.f;
#pragma unroll
        for (int q = 0; q < 4; ++q) {
            // A[m=col=d][k=g*8+t]; k>=16 lanes read garbage (nulled by xb=0)
            u[q] = __builtin_amdgcn_mfma_f32_16x16x32_bf16(
                af[q], xb, (f32x4){0.f, 0.f, 0.f, 0.f}, 0, 0, 0);
            float lp = vv[q].x * u[q][0] + vv[q].y * u[q][1]
                     + vv[q].z * u[q][2] + vv[q].w * u[q][3];
            lp += __shfl_xor(lp, 16);
            lp += __shfl_xor(lp, 32);      // all lanes: logit(b, n0+q)
            // no max-sub: |v|2<=0.5 (squash), |u|2<~8 => |logit|<=~4, f32-safe
            e[q] = __expf(lp);
            ps += e[q];
        }
        const int p = jj & 1;              // parity LDS buffer (WAR across j)
        if (g == 0) psum[p][w][col] = ps;
        lds_barrier();
        float Z = 0.f;
#pragma unroll
        for (int ww = 0; ww < 8; ++ww) Z += psum[p][ww][col];
        const float rz = __builtin_amdgcn_rcpf(Z);
#pragma unroll
        for (int q = 0; q < 4; ++q) {
            const float c = e[q] * rz;     // c stays f32 (no bf16 C round-trip)
#pragma unroll
            for (int r = 0; r < 4; ++r) acc[q][r] += c * u[q][r];
        }
    }

#pragma unroll
    for (int q = 0; q < 4; ++q) {
        int o[2] = { cvt_pk_bf16(acc[q][0], acc[q][1]),
                     cvt_pk_bf16(acc[q][2], acc[q][3]) };
        *(bf16x4*)(sp + (((size_t)chunk * 32 + n0 + q) * 64 + b) * 16 + g * 4) = *(bf16x4*)o;
    }
}

// fold NCH bf16 chunk partials, squash, update vsumT / write out. wave per (n,b).
// is_first: STORE vsum and apply the uniform-c 1/32 wsum0 does not pre-apply.
__global__ __launch_bounds__(256)
void reduce_k(const short* __restrict__ sp, float* __restrict__ vsumT,
              float* __restrict__ out, int is_first, int is_last) {
    const int t = threadIdx.x, lane = t & 63, w = t >> 6;
    const int q = blockIdx.x * 4 + w;       // 0..2047
    const int n = q >> 6, b = q & 63;
    const int d4 = lane & 3, ch = lane >> 2;   // ch 0..15

    float4 a = make_float4(0.f, 0.f, 0.f, 0.f);
#pragma unroll
    for (int m = 0; m < NCH / 16; ++m) {
        bf16x4 v = *(const bf16x4*)(sp + (((size_t)(ch + 16 * m) * 32 + n) * 64 + b) * 16 + d4 * 4);
        a.x += bf2f(v[0]); a.y += bf2f(v[1]); a.z += bf2f(v[2]); a.w += bf2f(v[3]);
    }
#pragma unroll
    for (int mk = 4; mk <= 32; mk <<= 1) {
        a.x += __shfl_xor(a.x, mk); a.y += __shfl_xor(a.y, mk);
        a.z += __shfl_xor(a.z, mk); a.w += __shfl_xor(a.w, mk);
    }
    const float sc = is_first ? 0.03125f : 1.0f;   // uniform c = 1/32 (pass 0)
    a.x *= sc; a.y *= sc; a.z *= sc; a.w *= sc;
    float tt = a.x * a.x + a.y * a.y + a.z * a.z + a.w * a.w;
    tt += __shfl_xor(tt, 1);
    tt += __shfl_xor(tt, 2);
    float s2 = tt + 1e-7f;
    float scale = sqrtf(s2) / (1.0f + s2);

    if (lane < 4) {
        float4 v = make_float4(a.x * scale, a.y * scale, a.z * scale, a.w * scale);
        if (is_last) {
            *(float4*)(out + ((size_t)b * 32 + n) * 16 + d4 * 4) = v;   // [b][n][d]
        } else {
            float* p = vsumT + ((size_t)n * 64 + b) * 16 + d4 * 4;      // [n][b][d]
            if (is_first) {
                *(float4*)p = v;
            } else {
                float4 o = *(const float4*)p;
                *(float4*)p = make_float4(o.x + v.x, o.y + v.y, o.z + v.z, o.w + v.w);
            }
        }
    }
}

extern "C" void kernel_launch(void* const* d_in, const int* in_sizes, int n_in,
                              void* d_out, int out_size, void* d_ws, size_t ws_size,
                              hipStream_t stream) {
    const float* x = (const float*)d_in[0];   // [64,2048,16]
    const float* W = (const float*)d_in[1];   // [32,2048,16,16]
    float* out = (float*)d_out;               // [64,32,16]

    char* wsb = (char*)d_ws;
    short* Wt    = (short*)(wsb);                        // 32 MB + slack
    short* xt    = (short*)(wsb + 33556480);             // 4.2 MB [j][b][16]
    short* sp    = (short*)(wsb + 46139392);             // 8.4 MB [chunk][n][b][d] bf16
    float* vsumT = (float*)(wsb + 54528000);             // 128 KB [n][b][d]

    cvt_x_t<<<512, 256, 0, stream>>>(x, xt);

    // pass 0: logits == 0 -> uniform c; W converted+transposed in-flight
    wsum0_cvt_k<<<dim3(NCH, 8), 256, 0, stream>>>(W, Wt, xt, sp);
    reduce_k<<<512, 256, 0, stream>>>(sp, vsumT, out, 1, 0);
    // pass 1 (fused logits+softmax+wsum)
    fused_pass_k<<<dim3(NCH, 4), 512, 0, stream>>>(Wt, xt, vsumT, sp);
    reduce_k<<<512, 256, 0, stream>>>(sp, vsumT, out, 0, 0);
    // pass 2
    fused_pass_k<<<dim3(NCH, 4), 512, 0, stream>>>(Wt, xt, vsumT, sp);
    reduce_k<<<512, 256, 0, stream>>>(sp, vsumT, out, 0, 1);
}

// Round 7
// 155.388 us; speedup vs baseline: 1.0156x; 1.0156x over previous
//
#include <hip/hip_runtime.h>
#include <hip/hip_bf16.h>

// Capsule dynamic routing, round 17.
// vs R16 (157.8 us): fused pass rebuilt on the 32x32x16 MFMA.
//  - One MFMA = (n-pair x 16 d) x 32 b, full K=16 (no zeroed B half, no
//    lane<32 masking). Wave = 4 n x 32 b via 2 MFMAs (was 4 MFMAs for 16 b).
//  - Block 512 thr = 8 waves = n-groups 0..7 -> ALL 32 n resident (R15 bug
//    re-checked: 4w+{0..3}, w=0..7 covers 0..31). grid(NCHF=256 chunks of
//    8 j, 2 b-halves) = 512 blocks = 2 blocks/CU, 4 waves/SIMD (R14 TLP).
//  - Wt read amplification 4x -> 2x (67 MB/pass); loads 327K -> 98K;
//    MFMAs 262K -> 65K; per-block barriers 16 -> 8.
// Layouts (guide-verified): 32x32 C/D col=lane&31, row=(reg&3)+8*(reg>>2)
// +4*(lane>>5); A/B [m|n=lane&31][k=(lane>>5)*8+t]. A rows 0..15 = n_pair
// lo (d=row), 16..31 = n_pair hi (d=row-16).
// Kept: cvt_x, wsum0_cvt (K=32 2-j packing), reduce_k (nch param), raw
// lds_barrier (R16-validated), cvt_pk packing, 1/32 folded into reduce.
//
// x[64][2048][16] f32, W[32][2048][16][16] f32 -> v[64][32][16] f32.

#define J_DIM 2048
#define NCH0 128           // wsum0 j-chunks (16 j each)
#define NCHF 256           // fused j-chunks (8 j each)

typedef __attribute__((ext_vector_type(8))) short bf16x8;
typedef __attribute__((ext_vector_type(4))) short bf16x4;
typedef __attribute__((ext_vector_type(4))) float f32x4;
typedef __attribute__((ext_vector_type(16))) float f32x16;

__device__ inline short f2bf(float f) {
    union { float f; unsigned u; } v; v.f = f;
    unsigned r = v.u + 0x7FFFu + ((v.u >> 16) & 1u);   // RNE
    return (short)(r >> 16);
}
__device__ inline float bf2f(short s) {
    union { unsigned u; float f; } v; v.u = ((unsigned)(unsigned short)s) << 16;
    return v.f;
}
// packed f32x2 -> bf16x2 (RNE), dst.lo = bf16(lo), dst.hi = bf16(hi)
__device__ inline int cvt_pk_bf16(float lo, float hi) {
    int r;
    asm("v_cvt_pk_bf16_f32 %0, %1, %2" : "=v"(r) : "v"(lo), "v"(hi));
    return r;
}
// Barrier WITHOUT the vmcnt(0) drain __syncthreads would emit (R16-validated).
__device__ inline void lds_barrier() {
    __builtin_amdgcn_sched_barrier(0);
    asm volatile("s_waitcnt lgkmcnt(0)" ::: "memory");
    __builtin_amdgcn_sched_barrier(0);
    __builtin_amdgcn_s_barrier();
    __builtin_amdgcn_sched_barrier(0);
}

// x[b][j][16] f32 -> xt[j][b][16] bf16. One thread per (b,j) row.
__global__ __launch_bounds__(256)
void cvt_x_t(const float* __restrict__ x, short* __restrict__ xt) {
    const int id = blockIdx.x * 256 + threadIdx.x;   // j fast for coalesced reads
    const int j = id & (J_DIM - 1), b = id >> 11;
    const float4* s = (const float4*)(x + ((size_t)b * J_DIM + j) * 16);
    float4 q0 = s[0], q1 = s[1], q2 = s[2], q3 = s[3];
    int pk[8];
    pk[0] = cvt_pk_bf16(q0.x, q0.y); pk[1] = cvt_pk_bf16(q0.z, q0.w);
    pk[2] = cvt_pk_bf16(q1.x, q1.y); pk[3] = cvt_pk_bf16(q1.z, q1.w);
    pk[4] = cvt_pk_bf16(q2.x, q2.y); pk[5] = cvt_pk_bf16(q2.z, q2.w);
    pk[6] = cvt_pk_bf16(q3.x, q3.y); pk[7] = cvt_pk_bf16(q3.z, q3.w);
    short* d = xt + ((size_t)j * 64 + b) * 16;
    *(bf16x8*)d = *(bf16x8*)pk;
    *(bf16x8*)(d + 8) = *(bf16x8*)&pk[4];
}

// Pass 0: read W f32 once (coalesced 1KB-row bursts), convert, write
// Wt[j][n][256] bf16, accumulate UNSCALED uniform-c partials (1/32 applied
// in reduce_k is_first). grid(NCH0, 8) x 256 thr.
__global__ __launch_bounds__(256)
void wsum0_cvt_k(const float* __restrict__ W, short* __restrict__ Wt,
                 const short* __restrict__ xt, short* __restrict__ sp) {
    const int t = threadIdx.x, lane = t & 63, w = t >> 6;
    const int col = lane & 15, g = lane >> 4;
    const int n = blockIdx.y * 4 + w;
    const int chunk = blockIdx.x;

    f32x4 acc[4];
#pragma unroll
    for (int bt = 0; bt < 4; ++bt) acc[bt] = (f32x4){0.f, 0.f, 0.f, 0.f};

#pragma unroll
    for (int jp = 0; jp < 8; ++jp) {
        const int jq = chunk * 16 + jp * 2 + (g >> 1);
        // lane's 8 f32 of W[n][jq] row; half-wave covers the full 1KB row
        const float4* wsrc = (const float4*)(W + ((size_t)n * J_DIM + jq) * 256 + col * 16 + (g & 1) * 8);
        float4 a = wsrc[0], b2 = wsrc[1];
        int pk[4];
        pk[0] = cvt_pk_bf16(a.x, a.y);   pk[1] = cvt_pk_bf16(a.z, a.w);
        pk[2] = cvt_pk_bf16(b2.x, b2.y); pk[3] = cvt_pk_bf16(b2.z, b2.w);
        bf16x8 af = *(bf16x8*)pk;
        *(bf16x8*)(Wt + ((size_t)jq * 32 + n) * 256 + col * 16 + (g & 1) * 8) = af;
#pragma unroll
        for (int bt = 0; bt < 4; ++bt) {
            const int b = bt * 16 + col;
            bf16x8 xr = *(const bf16x8*)(xt + ((size_t)jq * 64 + b) * 16 + (g & 1) * 8);
            acc[bt] = __builtin_amdgcn_mfma_f32_16x16x32_bf16(af, xr, acc[bt], 0, 0, 0);
        }
    }
#pragma unroll
    for (int bt = 0; bt < 4; ++bt) {
        int o[2] = { cvt_pk_bf16(acc[bt][0], acc[bt][1]),
                     cvt_pk_bf16(acc[bt][2], acc[bt][3]) };
        *(bf16x4*)(sp + (((size_t)chunk * 32 + n) * 64 + bt * 16 + col) * 16 + g * 4) = *(bf16x4*)o;
    }
}

// Fused routing pass (32x32x16 MFMA): sp[chunk][n][b][d] = sum_{j in chunk}
// softmax_n(v.u_hat) * u_hat for one 32-b half. grid(NCHF, 2) x 512 thr.
// wave w = n-group {4w..4w+3}; lane: b-col = lane&31, half h = lane>>5.
// MFMA0 rows: 0..15 -> (n0, d), 16..31 -> (n0+1, d); MFMA1 -> n0+2, n0+3.
// C/D reg r (half h): row = (r&3)+8*(r>>2)+4*h; regs 0..7 -> lo n (d=row),
// regs 8..15 -> hi n (d=row-16). Lane's d-set: {0..3,8..11}+4h.
__global__ __launch_bounds__(512, 4)
void fused_pass_k(const short* __restrict__ Wt, const short* __restrict__ xt,
                  const float* __restrict__ vsumT, short* __restrict__ sp) {
    const int t = threadIdx.x, lane = t & 63, w = t >> 6;   // w 0..7: n-group
    const int bc = lane & 31, h = lane >> 5;
    const int chunk = blockIdx.x;          // 8-j chunk
    const int bh = blockIdx.y;             // b-half
    const int b = bh * 32 + bc;
    const int n0 = w * 4;

    // A-row role of this lane: m = lane&31 -> (pair-sub n, d)
    const int nsub = bc >> 4;              // 0: lo n of pair, 1: hi n
    const int ad = bc & 15;                // d of the A row

    __shared__ float psum[2][8][32];       // [parity][wave][b-col]

    // per-lane slice of vsumT[n0+q][b][d], d in {0..3}+4h and {8..11}+4h
    float4 vvA[4], vvB[4];
#pragma unroll
    for (int q = 0; q < 4; ++q) {
        const float* vp = vsumT + ((size_t)(n0 + q) * 64 + b) * 16;
        vvA[q] = *(const float4*)(vp + 4 * h);
        vvB[q] = *(const float4*)(vp + 8 + 4 * h);
    }

    const f32x16 z16 = {0.f,0.f,0.f,0.f,0.f,0.f,0.f,0.f,
                        0.f,0.f,0.f,0.f,0.f,0.f,0.f,0.f};
    f32x16 acc0 = z16, acc1 = z16;

#pragma unroll 1
    for (int jj = 0; jj < 8; ++jj) {
        const int j = chunk * 8 + jj;
        // B: x[b][j][k], k = h*8+t (full K=16, no masking)
        const bf16x8 xb = *(const bf16x8*)(xt + ((size_t)j * 64 + b) * 16 + h * 8);
        // A: rows = (n-pair, d); lane loads Wt[j][n0+2p+nsub][ad*16 + h*8]
        const bf16x8 af0 = *(const bf16x8*)(Wt + ((size_t)j * 32 + n0 + nsub) * 256 + ad * 16 + h * 8);
        const bf16x8 af1 = *(const bf16x8*)(Wt + ((size_t)j * 32 + n0 + 2 + nsub) * 256 + ad * 16 + h * 8);

        f32x16 u0 = __builtin_amdgcn_mfma_f32_32x32x16_bf16(af0, xb, z16, 0, 0, 0);
        f32x16 u1 = __builtin_amdgcn_mfma_f32_32x32x16_bf16(af1, xb, z16, 0, 0, 0);

        // logits: lane's half-dot over its 8 d's, then combine halves
        float lp0 = vvA[0].x*u0[0] + vvA[0].y*u0[1] + vvA[0].z*u0[2] + vvA[0].w*u0[3]
                  + vvB[0].x*u0[4] + vvB[0].y*u0[5] + vvB[0].z*u0[6] + vvB[0].w*u0[7];
        float lp1 = vvA[1].x*u0[8] + vvA[1].y*u0[9] + vvA[1].z*u0[10] + vvA[1].w*u0[11]
                  + vvB[1].x*u0[12] + vvB[1].y*u0[13] + vvB[1].z*u0[14] + vvB[1].w*u0[15];
        float lp2 = vvA[2].x*u1[0] + vvA[2].y*u1[1] + vvA[2].z*u1[2] + vvA[2].w*u1[3]
                  + vvB[2].x*u1[4] + vvB[2].y*u1[5] + vvB[2].z*u1[6] + vvB[2].w*u1[7];
        float lp3 = vvA[3].x*u1[8] + vvA[3].y*u1[9] + vvA[3].z*u1[10] + vvA[3].w*u1[11]
                  + vvB[3].x*u1[12] + vvB[3].y*u1[13] + vvB[3].z*u1[14] + vvB[3].w*u1[15];
        lp0 += __shfl_xor(lp0, 32);
        lp1 += __shfl_xor(lp1, 32);
        lp2 += __shfl_xor(lp2, 32);
        lp3 += __shfl_xor(lp3, 32);
        // no max-sub: |v|2<=0.5 (squash), |u|2<~8 => |logit|<=~4, f32-safe
        const float e0 = __expf(lp0), e1 = __expf(lp1);
        const float e2 = __expf(lp2), e3 = __expf(lp3);

        const int p = jj & 1;              // parity LDS buffer (WAR across j)
        if (h == 0) psum[p][w][bc] = e0 + e1 + e2 + e3;
        lds_barrier();
        float Z = 0.f;
#pragma unroll
        for (int ww = 0; ww < 8; ++ww) Z += psum[p][ww][bc];
        const float rz = __builtin_amdgcn_rcpf(Z);
        const float c0 = e0 * rz, c1 = e1 * rz, c2 = e2 * rz, c3 = e3 * rz;
#pragma unroll
        for (int r = 0; r < 16; ++r) {
            acc0[r] += (r < 8 ? c0 : c1) * u0[r];
            acc1[r] += (r < 8 ? c2 : c3) * u1[r];
        }
    }

    // epilogue: reg r -> (n, d): regs 0..3 d=4h.., 4..7 d=8+4h.., 8..15 hi n
#pragma unroll
    for (int pair = 0; pair < 2; ++pair) {
        const f32x16 a = pair ? acc1 : acc0;
        const int nb = n0 + 2 * pair;
        short* lo = sp + (((size_t)chunk * 32 + nb) * 64 + b) * 16;
        short* hi = sp + (((size_t)chunk * 32 + nb + 1) * 64 + b) * 16;
        int o[2];
        o[0] = cvt_pk_bf16(a[0], a[1]);  o[1] = cvt_pk_bf16(a[2], a[3]);
        *(bf16x4*)(lo + 4 * h) = *(bf16x4*)o;
        o[0] = cvt_pk_bf16(a[4], a[5]);  o[1] = cvt_pk_bf16(a[6], a[7]);
        *(bf16x4*)(lo + 8 + 4 * h) = *(bf16x4*)o;
        o[0] = cvt_pk_bf16(a[8], a[9]);  o[1] = cvt_pk_bf16(a[10], a[11]);
        *(bf16x4*)(hi + 4 * h) = *(bf16x4*)o;
        o[0] = cvt_pk_bf16(a[12], a[13]); o[1] = cvt_pk_bf16(a[14], a[15]);
        *(bf16x4*)(hi + 8 + 4 * h) = *(bf16x4*)o;
    }
}

// fold nch bf16 chunk partials, squash, update vsumT / write out. wave per (n,b).
// is_first: STORE vsum and apply the uniform-c 1/32 wsum0 does not pre-apply.
__global__ __launch_bounds__(256)
void reduce_k(const short* __restrict__ sp, float* __restrict__ vsumT,
              float* __restrict__ out, int nch, int is_first, int is_last) {
    const int t = threadIdx.x, lane = t & 63, w = t >> 6;
    const int q = blockIdx.x * 4 + w;       // 0..2047
    const int n = q >> 6, b = q & 63;
    const int d4 = lane & 3, ch = lane >> 2;   // ch 0..15

    float4 a = make_float4(0.f, 0.f, 0.f, 0.f);
    for (int m = 0; m < (nch >> 4); ++m) {
        bf16x4 v = *(const bf16x4*)(sp + (((size_t)(ch + 16 * m) * 32 + n) * 64 + b) * 16 + d4 * 4);
        a.x += bf2f(v[0]); a.y += bf2f(v[1]); a.z += bf2f(v[2]); a.w += bf2f(v[3]);
    }
#pragma unroll
    for (int mk = 4; mk <= 32; mk <<= 1) {
        a.x += __shfl_xor(a.x, mk); a.y += __shfl_xor(a.y, mk);
        a.z += __shfl_xor(a.z, mk); a.w += __shfl_xor(a.w, mk);
    }
    const float sc = is_first ? 0.03125f : 1.0f;   // uniform c = 1/32 (pass 0)
    a.x *= sc; a.y *= sc; a.z *= sc; a.w *= sc;
    float tt = a.x * a.x + a.y * a.y + a.z * a.z + a.w * a.w;
    tt += __shfl_xor(tt, 1);
    tt += __shfl_xor(tt, 2);
    float s2 = tt + 1e-7f;
    float scale = sqrtf(s2) / (1.0f + s2);

    if (lane < 4) {
        float4 v = make_float4(a.x * scale, a.y * scale, a.z * scale, a.w * scale);
        if (is_last) {
            *(float4*)(out + ((size_t)b * 32 + n) * 16 + d4 * 4) = v;   // [b][n][d]
        } else {
            float* p = vsumT + ((size_t)n * 64 + b) * 16 + d4 * 4;      // [n][b][d]
            if (is_first) {
                *(float4*)p = v;
            } else {
                float4 o = *(const float4*)p;
                *(float4*)p = make_float4(o.x + v.x, o.y + v.y, o.z + v.z, o.w + v.w);
            }
        }
    }
}

extern "C" void kernel_launch(void* const* d_in, const int* in_sizes, int n_in,
                              void* d_out, int out_size, void* d_ws, size_t ws_size,
                              hipStream_t stream) {
    const float* x = (const float*)d_in[0];   // [64,2048,16]
    const float* W = (const float*)d_in[1];   // [32,2048,16,16]
    float* out = (float*)d_out;               // [64,32,16]

    char* wsb = (char*)d_ws;
    short* Wt    = (short*)(wsb);                        // 33.5 MB [j][n][256]
    short* xt    = (short*)(wsb + 33556480);             // 4.2 MB [j][b][16]
    short* sp    = (short*)(wsb + 37750784);             // 16.78 MB [chunk<=256][n][b][d]
    float* vsumT = (float*)(wsb + 54528000);             // 128 KB [n][b][d]

    cvt_x_t<<<512, 256, 0, stream>>>(x, xt);

    // pass 0: logits == 0 -> uniform c; W converted+transposed in-flight
    wsum0_cvt_k<<<dim3(NCH0, 8), 256, 0, stream>>>(W, Wt, xt, sp);
    reduce_k<<<512, 256, 0, stream>>>(sp, vsumT, out, NCH0, 1, 0);
    // pass 1 (fused logits+softmax+wsum, 32x32 MFMA)
    fused_pass_k<<<dim3(NCHF, 2), 512, 0, stream>>>(Wt, xt, vsumT, sp);
    reduce_k<<<512, 256, 0, stream>>>(sp, vsumT, out, NCHF, 0, 0);
    // pass 2
    fused_pass_k<<<dim3(NCHF, 2), 512, 0, stream>>>(Wt, xt, vsumT, sp);
    reduce_k<<<512, 256, 0, stream>>>(sp, vsumT, out, NCHF, 0, 1);
}